// Round 9
// baseline (1336.525 us; speedup 1.0000x reference)
//
#include <hip/hip_runtime.h>
#include <hip/hip_bf16.h>

#define BB 256
#define NN 2048
#define NSTEPS 64
#define DT_C 0.1f

typedef __attribute__((ext_vector_type(8))) short short8;
typedef __attribute__((ext_vector_type(4))) short short4_t;
typedef __attribute__((ext_vector_type(4))) float floatx4;
typedef __attribute__((ext_vector_type(4))) float f32x4;

__device__ __forceinline__ floatx4 mfma_bf16(short8 a, short8 b, floatx4 c) {
  return __builtin_amdgcn_mfma_f32_16x16x32_bf16(a, b, c, 0, 0, 0);
}

__device__ __forceinline__ short bf16bits(float f) {
  __hip_bfloat16 h = __float2bfloat16(f);
  return *reinterpret_cast<short*>(&h);
}

// ---------------- fragment-major layouts (verified rounds 4-8) ----------------
// frag(rf=row>>4, kc=k>>5), frag idx = rf*64+kc, 512 bf16/frag (1KB contiguous);
// in-frag: lane = (row&15) | (((k>>3)&3)<<4), elem = k&7.

// one-time: both f32 NxN weights -> bf16 fragment-major (grid covers W then T)
__global__ __launch_bounds__(256) void convert_kernel(
    const float* __restrict__ Ww, __hip_bfloat16* __restrict__ Wf,
    const float* __restrict__ Tw, __hip_bfloat16* __restrict__ Tf, int half) {
  int bid = blockIdx.x;
  const float* src = Ww;
  __hip_bfloat16* dst = Wf;
  if (bid >= half) { bid -= half; src = Tw; dst = Tf; }
  const int g = bid * 256 + threadIdx.x;
  const int frag = g >> 6, l = g & 63;
  const int j = (frag >> 6) * 16 + (l & 15);
  const int k = (frag & 63) * 32 + (l >> 4) * 8;
  const float* s = src + (size_t)j * NN + k;
  short8 v;
#pragma unroll
  for (int e = 0; e < 8; ++e) v[e] = bf16bits(s[e]);
  *(short8*)((short*)dst + (size_t)g * 8) = v;
}

__global__ __launch_bounds__(256) void init_kernel(
    const float* __restrict__ x0,
    __hip_bfloat16* __restrict__ U, __hip_bfloat16* __restrict__ PSI) {
  const int i = blockIdx.x * 256 + threadIdx.x;
  const int b = i >> 11, j = i & (NN - 1);
  const float r = fmaxf(x0[i], 0.f);
  const int dl = (b & 15) | (((j >> 3) & 3) << 4);
  const size_t fo = ((size_t)((b >> 4) * 64 + (j >> 5))) * 512 + dl * 8 + (j & 7);
  U[fo] = __float2bfloat16(r * r);   // u0 = relu(x0)*relu(x0)  (phi==g at t=0)
  PSI[fo] = __float2bfloat16(r);
}

#define LOADST(S, kc) \
  S##a0 = *(const short8*)(aP0 + (size_t)(kc) * 512); \
  S##a1 = *(const short8*)(aP1 + (size_t)(kc) * 512); \
  S##a2 = *(const short8*)(aP2 + (size_t)(kc) * 512); \
  S##a3 = *(const short8*)(aP3 + (size_t)(kc) * 512); \
  S##b0 = *(const short8*)(bP0 + (size_t)(kc) * 512); \
  S##b1 = *(const short8*)(bP1 + (size_t)(kc) * 512);
#define DOMFMA(S) \
  acc00 = mfma_bf16(S##a0, S##b0, acc00); acc01 = mfma_bf16(S##a0, S##b1, acc01); \
  acc10 = mfma_bf16(S##a1, S##b0, acc10); acc11 = mfma_bf16(S##a1, S##b1, acc11); \
  acc20 = mfma_bf16(S##a2, S##b0, acc20); acc21 = mfma_bf16(S##a2, S##b1, acc21); \
  acc30 = mfma_bf16(S##a3, S##b0, acc30); acc31 = mfma_bf16(S##a3, S##b1, acc31);

// Block: 64 rows x 32 cols, BOTH GEMMs, grid 256 = 1 block/CU.
// 8 waves: wv = g*4 + h;  g: 0=W-GEMM(A=U), 1=T-GEMM(A=PSI); h: K-QUARTER (512).
// Each wave computes the full 64x32 tile over its K-quarter: 6 streams
// (4 A row-frags + 2 B col-frags) -- ALL 48 streams in the block are pairwise
// disjoint => issued bytes == unique bytes (768 KB/block, -25% vs R7).
__global__ __launch_bounds__(512, 2) void step_kernel(
    const __hip_bfloat16* __restrict__ Wf, const __hip_bfloat16* __restrict__ Tf,
    const float* __restrict__ Wb, const float* __restrict__ Tb,
    const float* __restrict__ wp2s, const float* __restrict__ ws2p,
    const float* __restrict__ fri,
    const float* __restrict__ Xprev, const float2* __restrict__ SPprev,
    const __hip_bfloat16* __restrict__ Uprev, const __hip_bfloat16* __restrict__ PSprev,
    float2* __restrict__ SPnew,
    __hip_bfloat16* __restrict__ Unew, __hip_bfloat16* __restrict__ PSnew,
    float* __restrict__ xsout, float* __restrict__ outFin, int first, int last) {
  // 8 waves x 64 rows x 36 cols f32 partials; stride 36 keeps f32x4 16B-aligned,
  // quarter-wave phasing keeps store/read <=2-way bank aliasing (free).
  __shared__ float eb[8][64][36];   // 72 KB

  const int tid = threadIdx.x;
  const int lane = tid & 63, wv = tid >> 6;
  const int lane15 = lane & 15, kq = lane >> 4;
  const int g = wv >> 2, h = wv & 3;

  // XCD-aware bijective swizzle: XCD x owns col-tiles x*8..x*8+7 (2MB weights in L2).
  const int sb = ((blockIdx.x & 7) << 5) + (blockIdx.x >> 3);
  const int colt = sb >> 2, rowt = sb & 3;       // 64 col-tiles x 4 row-tiles
  const int b0 = rowt * 64, j0 = colt * 32;

  // ---- epilogue preloads: issue BEFORE the GEMM so latency hides under it ----
  const int erow = tid >> 3;          // 0..63
  const int c4 = (tid & 7) << 2;      // 0,4,...,28
  const int ej = j0 + c4;
  const size_t eidx = (size_t)(b0 + erow) * NN + ej;
  const f32x4 Wb4 = *(const f32x4*)(Wb + ej);
  const f32x4 Tb4 = *(const f32x4*)(Tb + ej);
  const f32x4 wp4 = *(const f32x4*)(wp2s + ej);
  const f32x4 ws4 = *(const f32x4*)(ws2p + ej);
  const f32x4 fr4 = *(const f32x4*)(fri + eidx);
  const f32x4 xv4 = *(const f32x4*)(Xprev + eidx);
  f32x4 sv4, pv4;
  if (first) {
    sv4 = xv4; pv4 = xv4;
  } else {
#pragma unroll
    for (int e = 0; e < 4; e += 2) {
      const f32x4 t0 = *(const f32x4*)(SPprev + eidx + e);      // {s0,p0,s1,p1}
      sv4[e] = t0[0]; pv4[e] = t0[1]; sv4[e + 1] = t0[2]; pv4[e + 1] = t0[3];
    }
  }

  // ---- GEMM streams (all disjoint) ----
  const short* Af = (const short*)(g == 0 ? Uprev : PSprev);
  const short* Bf = (const short*)(g == 0 ? Wf : Tf);
  const int rf0 = rowt * 4;            // A row-frag base (64 rows = 4 frags)
  const int cf0 = colt * 2;            // B col-frag base (32 cols = 2 frags)
  const int kcb = h * 16;              // K-quarter base (frag-k units)

  const short* aP0 = Af + ((size_t)(rf0 + 0) * 64 + kcb) * 512 + lane * 8;
  const short* aP1 = Af + ((size_t)(rf0 + 1) * 64 + kcb) * 512 + lane * 8;
  const short* aP2 = Af + ((size_t)(rf0 + 2) * 64 + kcb) * 512 + lane * 8;
  const short* aP3 = Af + ((size_t)(rf0 + 3) * 64 + kcb) * 512 + lane * 8;
  const short* bP0 = Bf + ((size_t)(cf0 + 0) * 64 + kcb) * 512 + lane * 8;
  const short* bP1 = Bf + ((size_t)(cf0 + 1) * 64 + kcb) * 512 + lane * 8;

  floatx4 acc00 = {0.f,0.f,0.f,0.f}, acc01 = {0.f,0.f,0.f,0.f};
  floatx4 acc10 = {0.f,0.f,0.f,0.f}, acc11 = {0.f,0.f,0.f,0.f};
  floatx4 acc20 = {0.f,0.f,0.f,0.f}, acc21 = {0.f,0.f,0.f,0.f};
  floatx4 acc30 = {0.f,0.f,0.f,0.f}, acc31 = {0.f,0.f,0.f,0.f};

  short8 Aa0, Aa1, Aa2, Aa3, Ab0, Ab1;
  short8 Ba0, Ba1, Ba2, Ba3, Bb0, Bb1;
  short8 Ca0, Ca1, Ca2, Ca3, Cb0, Cb1;
  LOADST(A, 0) LOADST(B, 1) LOADST(C, 2)
  for (int kc = 0; kc < 12; kc += 3) {   // compute 0..11, load 3..14
    DOMFMA(A) LOADST(A, kc + 3)
    DOMFMA(B) LOADST(B, kc + 4)
    DOMFMA(C) LOADST(C, kc + 5)
  }
  DOMFMA(A) LOADST(A, 15)                // compute 12, load 15
  DOMFMA(B) DOMFMA(C) DOMFMA(A)          // 16 k-iters total, no OOB loads

  // publish partials: eb[wv][row][col] (C-frag: row=kq*4+reg, col=lane15)
#pragma unroll
  for (int r = 0; r < 4; ++r) {
    eb[wv][kq * 4 + r][lane15]       = acc00[r];
    eb[wv][kq * 4 + r][16 + lane15]  = acc01[r];
    eb[wv][16 + kq * 4 + r][lane15]      = acc10[r];
    eb[wv][16 + kq * 4 + r][16 + lane15] = acc11[r];
    eb[wv][32 + kq * 4 + r][lane15]      = acc20[r];
    eb[wv][32 + kq * 4 + r][16 + lane15] = acc21[r];
    eb[wv][48 + kq * 4 + r][lane15]      = acc30[r];
    eb[wv][48 + kq * 4 + r][16 + lane15] = acc31[r];
  }
  __syncthreads();

  // ---- vector epilogue: thread owns (row erow, cols ej..ej+3) ----
  f32x4 m1, m2;
  {
    const f32x4 p0 = *(const f32x4*)&eb[0][erow][c4];
    const f32x4 p1 = *(const f32x4*)&eb[1][erow][c4];
    const f32x4 p2 = *(const f32x4*)&eb[2][erow][c4];
    const f32x4 p3 = *(const f32x4*)&eb[3][erow][c4];
    const f32x4 q0 = *(const f32x4*)&eb[4][erow][c4];
    const f32x4 q1 = *(const f32x4*)&eb[5][erow][c4];
    const f32x4 q2 = *(const f32x4*)&eb[6][erow][c4];
    const f32x4 q3 = *(const f32x4*)&eb[7][erow][c4];
    m1 = (p0 + p1) + (p2 + p3);
    m2 = (q0 + q1) + (q2 + q3);
  }
  f32x4 xn4;
  short4_t u4, ps4;
#pragma unroll
  for (int e = 0; e < 4; e += 2) {
    f32x4 sp;
#pragma unroll
    for (int q = 0; q < 2; ++q) {
      const int ee = e + q;
      const float xv = xv4[ee], s = sv4[ee], p = pv4[ee];
      const float phi = fmaxf(xv, 0.f), gg = fmaxf(s, 0.f), psi = fmaxf(p, 0.f);
      const float xn = xv + DT_C * (-xv + m1[ee] + Wb4[ee]) * fr4[ee];
      const float sn = p + DT_C * (-s + wp4[ee] * psi + phi);  // base is p (as in source)
      const float pn = p + DT_C * (-p + m2[ee] + Tb4[ee] + ws4[ee] * gg);
      xn4[ee] = xn;
      sp[q * 2] = sn; sp[q * 2 + 1] = pn;
      u4[ee] = bf16bits(fmaxf(xn, 0.f) * fmaxf(sn, 0.f));
      ps4[ee] = bf16bits(fmaxf(pn, 0.f));
    }
    *(f32x4*)(SPnew + eidx + e) = sp;    // {s,p,s,p}
  }
  *(f32x4*)(xsout + eidx) = xn4;
  if (last) *(f32x4*)(outFin + eidx) = xn4;
  // next-step operands, fragment-major (4 consecutive elems share dl group)
  const int b = b0 + erow;
  const int dl = (b & 15) | (((ej >> 3) & 3) << 4);
  const int fob = ((b >> 4) * 64 + (ej >> 5)) * 512 + dl * 8 + (ej & 7);
  *(short4_t*)((short*)Unew + fob) = u4;
  *(short4_t*)((short*)PSnew + fob) = ps4;
}

extern "C" void kernel_launch(void* const* d_in, const int* in_sizes, int n_in,
                              void* d_out, int out_size, void* d_ws, size_t ws_size,
                              hipStream_t stream) {
  const float* x0   = (const float*)d_in[0];
  const float* fri  = (const float*)d_in[1];
  const float* Ww   = (const float*)d_in[2];
  const float* Wb   = (const float*)d_in[3];
  const float* Tw   = (const float*)d_in[4];
  const float* Tb   = (const float*)d_in[5];
  const float* wp2s = (const float*)d_in[6];
  const float* ws2p = (const float*)d_in[7];
  float* out = (float*)d_out;

  const size_t BN = (size_t)BB * NN;
  const size_t NW = (size_t)NN * NN;
  float2* SP = (float2*)d_ws;                    // interleaved {s,p}
  __hip_bfloat16* U0  = (__hip_bfloat16*)(SP + BN);
  __hip_bfloat16* U1  = U0 + BN;
  __hip_bfloat16* PS0 = U1 + BN;
  __hip_bfloat16* PS1 = PS0 + BN;
  __hip_bfloat16* Wf  = PS1 + BN;
  __hip_bfloat16* Tf  = Wf + NW;

  const int chalf = (int)(NW / 2048);
  convert_kernel<<<2 * chalf, 256, 0, stream>>>(Ww, Wf, Tw, Tf, chalf);
  init_kernel<<<(int)(BN / 256), 256, 0, stream>>>(x0, U0, PS0);

  float* xs = out + BN;  // xs[t] = out + BN + t*BN
  for (int t = 0; t < NSTEPS; ++t) {
    const float* Xprev = (t == 0) ? x0 : (xs + (size_t)(t - 1) * BN);
    const __hip_bfloat16* Uprev  = (t & 1) ? U1 : U0;
    const __hip_bfloat16* PSprev = (t & 1) ? PS1 : PS0;
    __hip_bfloat16* Unew  = (t & 1) ? U0 : U1;
    __hip_bfloat16* PSnew = (t & 1) ? PS0 : PS1;
    step_kernel<<<256, 512, 0, stream>>>(Wf, Tf, Wb, Tb, wp2s, ws2p, fri,
                                         Xprev, SP, Uprev, PSprev,
                                         SP, Unew, PSnew,
                                         xs + (size_t)t * BN, out,
                                         (t == 0) ? 1 : 0,
                                         (t == NSTEPS - 1) ? 1 : 0);
  }
}

// Round 10
// 1328.159 us; speedup vs baseline: 1.0063x; 1.0063x over previous
//
#include <hip/hip_runtime.h>
#include <hip/hip_bf16.h>

#define BB 256
#define NN 2048
#define NSTEPS 64
#define DT_C 0.1f

typedef __attribute__((ext_vector_type(8))) short short8;
typedef __attribute__((ext_vector_type(4))) short short4_t;
typedef __attribute__((ext_vector_type(4))) float floatx4;
typedef __attribute__((ext_vector_type(4))) float f32x4;

__device__ __forceinline__ floatx4 mfma_bf16(short8 a, short8 b, floatx4 c) {
  return __builtin_amdgcn_mfma_f32_16x16x32_bf16(a, b, c, 0, 0, 0);
}

__device__ __forceinline__ short bf16bits(float f) {
  __hip_bfloat16 h = __float2bfloat16(f);
  return *reinterpret_cast<short*>(&h);
}

// Cross-step data is invalidated at every kernel boundary anyway; nt stores
// avoid dirtying L2 (less end-of-kernel writeback, less weight/A eviction).
__device__ __forceinline__ f32x4 nt_load4(const float* p) {
  return __builtin_nontemporal_load((const f32x4*)p);
}
__device__ __forceinline__ void nt_store4(float* p, f32x4 v) {
  __builtin_nontemporal_store(v, (f32x4*)p);
}
__device__ __forceinline__ void nt_store_s4(short* p, short4_t v) {
  __builtin_nontemporal_store(v, (short4_t*)p);
}

// ---------------- fragment-major layouts (verified rounds 4-9) ----------------
// frag(rf=row>>4, kc=k>>5), frag idx = rf*64+kc, 512 bf16/frag (1KB contiguous);
// in-frag: lane = (row&15) | (((k>>3)&3)<<4), elem = k&7.

// one-time: both f32 NxN weights -> bf16 fragment-major (grid covers W then T)
__global__ __launch_bounds__(256) void convert_kernel(
    const float* __restrict__ Ww, __hip_bfloat16* __restrict__ Wf,
    const float* __restrict__ Tw, __hip_bfloat16* __restrict__ Tf, int half) {
  int bid = blockIdx.x;
  const float* src = Ww;
  __hip_bfloat16* dst = Wf;
  if (bid >= half) { bid -= half; src = Tw; dst = Tf; }
  const int g = bid * 256 + threadIdx.x;
  const int frag = g >> 6, l = g & 63;
  const int j = (frag >> 6) * 16 + (l & 15);
  const int k = (frag & 63) * 32 + (l >> 4) * 8;
  const float* s = src + (size_t)j * NN + k;
  short8 v;
#pragma unroll
  for (int e = 0; e < 8; ++e) v[e] = bf16bits(s[e]);
  *(short8*)((short*)dst + (size_t)g * 8) = v;
}

__global__ __launch_bounds__(256) void init_kernel(
    const float* __restrict__ x0,
    __hip_bfloat16* __restrict__ U, __hip_bfloat16* __restrict__ PSI) {
  const int i = blockIdx.x * 256 + threadIdx.x;
  const int b = i >> 11, j = i & (NN - 1);
  const float r = fmaxf(x0[i], 0.f);
  const int dl = (b & 15) | (((j >> 3) & 3) << 4);
  const size_t fo = ((size_t)((b >> 4) * 64 + (j >> 5))) * 512 + dl * 8 + (j & 7);
  U[fo] = __float2bfloat16(r * r);   // u0 = relu(x0)*relu(x0)  (phi==g at t=0)
  PSI[fo] = __float2bfloat16(r);
}

#define LOADST(S, kc) \
  S##a0 = *(const short8*)(aP0 + (size_t)(kc) * 512); \
  S##a1 = *(const short8*)(aP1 + (size_t)(kc) * 512); \
  S##b0 = *(const short8*)(bP0 + (size_t)(kc) * 512); \
  S##b1 = *(const short8*)(bP1 + (size_t)(kc) * 512);
#define DOMFMA(S) \
  acc00 = mfma_bf16(S##a0, S##b0, acc00); \
  acc01 = mfma_bf16(S##a0, S##b1, acc01); \
  acc10 = mfma_bf16(S##a1, S##b0, acc10); \
  acc11 = mfma_bf16(S##a1, S##b1, acc11);

// Block: 64 rows x 32 cols, BOTH GEMMs, grid 256 = 1 block/CU. 8 waves:
//   wv = g*4 + rw*2 + h; g: GEMM, rw: row-half, h: K-half. (R7 structure.)
__global__ __launch_bounds__(512, 2) void step_kernel(
    const __hip_bfloat16* __restrict__ Wf, const __hip_bfloat16* __restrict__ Tf,
    const float* __restrict__ Wb, const float* __restrict__ Tb,
    const float* __restrict__ wp2s, const float* __restrict__ ws2p,
    const float* __restrict__ fri,
    const float* __restrict__ Xprev, const float2* __restrict__ SPprev,
    const __hip_bfloat16* __restrict__ Uprev, const __hip_bfloat16* __restrict__ PSprev,
    float2* __restrict__ SPnew,
    __hip_bfloat16* __restrict__ Unew, __hip_bfloat16* __restrict__ PSnew,
    float* __restrict__ xsout, float* __restrict__ outFin, int first, int last) {
  __shared__ float eb[8][32][36];   // per-wave 32x32 f32 partials, padded

  const int tid = threadIdx.x;
  const int lane = tid & 63, wv = tid >> 6;
  const int lane15 = lane & 15, kq = lane >> 4;
  const int g = wv >> 2, rw = (wv >> 1) & 1, h = wv & 1;

  // XCD-aware bijective swizzle: XCD x owns col-tiles x*8..x*8+7 (2MB weights in L2).
  const int sb = ((blockIdx.x & 7) << 5) + (blockIdx.x >> 3);
  const int colt = sb >> 2, rowt = sb & 3;
  const int b0 = rowt * 64, j0 = colt * 32;

  // ---- epilogue preloads: issue BEFORE the GEMM so latency hides under it ----
  const int erow = tid >> 3;          // 0..63
  const int c4 = (tid & 7) << 2;      // 0,4,...,28
  const int ej = j0 + c4;
  const size_t eidx = (size_t)(b0 + erow) * NN + ej;
  const f32x4 Wb4 = *(const f32x4*)(Wb + ej);
  const f32x4 Tb4 = *(const f32x4*)(Tb + ej);
  const f32x4 wp4 = *(const f32x4*)(wp2s + ej);
  const f32x4 ws4 = *(const f32x4*)(ws2p + ej);
  const f32x4 fr4 = *(const f32x4*)(fri + eidx);
  const f32x4 xv4 = nt_load4(Xprev + eidx);
  f32x4 sv4, pv4;
  if (first) {
    sv4 = xv4; pv4 = xv4;
  } else {
#pragma unroll
    for (int e = 0; e < 4; e += 2) {
      const f32x4 t0 = __builtin_nontemporal_load((const f32x4*)(SPprev + eidx + e));
      sv4[e] = t0[0]; pv4[e] = t0[1]; sv4[e + 1] = t0[2]; pv4[e + 1] = t0[3];
    }
  }

  // ---- GEMM streams (disjoint per wave; B-pair overlap is L1-served) ----
  const short* Af = (const short*)(g == 0 ? Uprev : PSprev);
  const short* Bf = (const short*)(g == 0 ? Wf : Tf);
  const int rf0 = rowt * 4 + rw * 2;   // A row-frag base (rows rw*32..+31)
  const int cf0 = colt * 2;            // B col-frag base (cols j0..+31)
  const int kcb = h * 32;              // K-half base (frag-k units)

  const short* aP0 = Af + ((size_t)rf0 * 64 + kcb) * 512 + lane * 8;
  const short* aP1 = Af + ((size_t)(rf0 + 1) * 64 + kcb) * 512 + lane * 8;
  const short* bP0 = Bf + ((size_t)cf0 * 64 + kcb) * 512 + lane * 8;
  const short* bP1 = Bf + ((size_t)(cf0 + 1) * 64 + kcb) * 512 + lane * 8;

  floatx4 acc00 = {0.f, 0.f, 0.f, 0.f}, acc01 = {0.f, 0.f, 0.f, 0.f};
  floatx4 acc10 = {0.f, 0.f, 0.f, 0.f}, acc11 = {0.f, 0.f, 0.f, 0.f};

  short8 Aa0, Aa1, Ab0, Ab1, Ba0, Ba1, Bb0, Bb1, Ca0, Ca1, Cb0, Cb1;
  short8 Da0, Da1, Db0, Db1, Ea0, Ea1, Eb0, Eb1, Fa0, Fa1, Fb0, Fb1;
  LOADST(A, 0) LOADST(B, 1) LOADST(C, 2) LOADST(D, 3) LOADST(E, 4) LOADST(F, 5)
  for (int kc = 0; kc < 24; kc += 6) {   // compute 0..23, load 6..29
    DOMFMA(A) LOADST(A, kc + 6)
    DOMFMA(B) LOADST(B, kc + 7)
    DOMFMA(C) LOADST(C, kc + 8)
    DOMFMA(D) LOADST(D, kc + 9)
    DOMFMA(E) LOADST(E, kc + 10)
    DOMFMA(F) LOADST(F, kc + 11)
  }
  DOMFMA(A) LOADST(A, 30)
  DOMFMA(B) LOADST(B, 31)
  DOMFMA(C) DOMFMA(D) DOMFMA(E) DOMFMA(F)
  DOMFMA(A) DOMFMA(B)                    // 32 k-iters total, no OOB loads

  // publish partials: eb[wv][local row][local col]
#pragma unroll
  for (int r = 0; r < 4; ++r) {
    eb[wv][kq * 4 + r][lane15] = acc00[r];
    eb[wv][kq * 4 + r][16 + lane15] = acc01[r];
    eb[wv][16 + kq * 4 + r][lane15] = acc10[r];
    eb[wv][16 + kq * 4 + r][16 + lane15] = acc11[r];
  }
  __syncthreads();

  // ---- vector epilogue: thread owns (row erow, cols ej..ej+3) ----
  const int rl = erow & 31, rh = erow >> 5;
  f32x4 m1, m2;
  {
    const f32x4 p0 = *(const f32x4*)&eb[rh * 2 + 0][rl][c4];
    const f32x4 p1 = *(const f32x4*)&eb[rh * 2 + 1][rl][c4];
    const f32x4 q0 = *(const f32x4*)&eb[4 + rh * 2 + 0][rl][c4];
    const f32x4 q1 = *(const f32x4*)&eb[4 + rh * 2 + 1][rl][c4];
    m1 = p0 + p1;
    m2 = q0 + q1;
  }
  f32x4 xn4;
  short4_t u4, ps4;
#pragma unroll
  for (int e = 0; e < 4; e += 2) {
    f32x4 sp;
#pragma unroll
    for (int q = 0; q < 2; ++q) {
      const int ee = e + q;
      const float xv = xv4[ee], s = sv4[ee], p = pv4[ee];
      const float phi = fmaxf(xv, 0.f), gg = fmaxf(s, 0.f), psi = fmaxf(p, 0.f);
      const float xn = xv + DT_C * (-xv + m1[ee] + Wb4[ee]) * fr4[ee];
      const float sn = p + DT_C * (-s + wp4[ee] * psi + phi);  // base is p (as in source)
      const float pn = p + DT_C * (-p + m2[ee] + Tb4[ee] + ws4[ee] * gg);
      xn4[ee] = xn;
      sp[q * 2] = sn; sp[q * 2 + 1] = pn;
      u4[ee] = bf16bits(fmaxf(xn, 0.f) * fmaxf(sn, 0.f));
      ps4[ee] = bf16bits(fmaxf(pn, 0.f));
    }
    nt_store4((float*)(SPnew + eidx + e), sp);    // {s,p,s,p}
  }
  nt_store4(xsout + eidx, xn4);
  if (last) nt_store4(outFin + eidx, xn4);
  // next-step operands, fragment-major (4 consecutive elems share dl group)
  const int b = b0 + erow;
  const int dl = (b & 15) | (((ej >> 3) & 3) << 4);
  const int fob = ((b >> 4) * 64 + (ej >> 5)) * 512 + dl * 8 + (ej & 7);
  nt_store_s4((short*)Unew + fob, u4);
  nt_store_s4((short*)PSnew + fob, ps4);
}

extern "C" void kernel_launch(void* const* d_in, const int* in_sizes, int n_in,
                              void* d_out, int out_size, void* d_ws, size_t ws_size,
                              hipStream_t stream) {
  const float* x0   = (const float*)d_in[0];
  const float* fri  = (const float*)d_in[1];
  const float* Ww   = (const float*)d_in[2];
  const float* Wb   = (const float*)d_in[3];
  const float* Tw   = (const float*)d_in[4];
  const float* Tb   = (const float*)d_in[5];
  const float* wp2s = (const float*)d_in[6];
  const float* ws2p = (const float*)d_in[7];
  float* out = (float*)d_out;

  const size_t BN = (size_t)BB * NN;
  const size_t NW = (size_t)NN * NN;
  float2* SP = (float2*)d_ws;                    // interleaved {s,p}
  __hip_bfloat16* U0  = (__hip_bfloat16*)(SP + BN);
  __hip_bfloat16* U1  = U0 + BN;
  __hip_bfloat16* PS0 = U1 + BN;
  __hip_bfloat16* PS1 = PS0 + BN;
  __hip_bfloat16* Wf  = PS1 + BN;
  __hip_bfloat16* Tf  = Wf + NW;

  const int chalf = (int)(NW / 2048);
  convert_kernel<<<2 * chalf, 256, 0, stream>>>(Ww, Wf, Tw, Tf, chalf);
  init_kernel<<<(int)(BN / 256), 256, 0, stream>>>(x0, U0, PS0);

  float* xs = out + BN;  // xs[t] = out + BN + t*BN
  for (int t = 0; t < NSTEPS; ++t) {
    const float* Xprev = (t == 0) ? x0 : (xs + (size_t)(t - 1) * BN);
    const __hip_bfloat16* Uprev  = (t & 1) ? U1 : U0;
    const __hip_bfloat16* PSprev = (t & 1) ? PS1 : PS0;
    __hip_bfloat16* Unew  = (t & 1) ? U0 : U1;
    __hip_bfloat16* PSnew = (t & 1) ? PS0 : PS1;
    step_kernel<<<256, 512, 0, stream>>>(Wf, Tf, Wb, Tb, wp2s, ws2p, fri,
                                         Xprev, SP, Uprev, PSprev,
                                         SP, Unew, PSnew,
                                         xs + (size_t)t * BN, out,
                                         (t == 0) ? 1 : 0,
                                         (t == NSTEPS - 1) ? 1 : 0);
  }
}

// Round 11
// 852.532 us; speedup vs baseline: 1.5677x; 1.5579x over previous
//
#include <hip/hip_runtime.h>
#include <hip/hip_bf16.h>

#define BB 256
#define NN 2048
#define NSTEPS 64
#define DT_C 0.1f
// fp8 scaling: weights x512 (2^9), activations x8 (2^3); acc / 4096 (exact).
#define WSCALE 512.0f
#define ASCALE 8.0f
#define ACC_INV (1.0f / 4096.0f)

typedef __attribute__((ext_vector_type(4))) float floatx4;
typedef __attribute__((ext_vector_type(4))) float f32x4;

__device__ __forceinline__ floatx4 mfma_fp8(long long a, long long b, floatx4 c) {
  return __builtin_amdgcn_mfma_f32_16x16x32_fp8_fp8(a, b, c, 0, 0, 0);
}

// pack 2 f32 -> 2 fp8 e4m3 bytes (low half), 4 f32 -> 4 bytes
__device__ __forceinline__ unsigned pack4_fp8(float a, float b, float c, float d) {
  int lo = __builtin_amdgcn_cvt_pk_fp8_f32(a, b, 0, false);    // bytes 0,1
  int r  = __builtin_amdgcn_cvt_pk_fp8_f32(c, d, lo, true);    // bytes 2,3
  return (unsigned)r;
}
__device__ __forceinline__ unsigned char fp8byte(float v) {
  return (unsigned char)(__builtin_amdgcn_cvt_pk_fp8_f32(v, 0.f, 0, false) & 0xff);
}

// ---------------- fragment-major fp8 layouts ----------------
// Same lane mapping as the verified bf16 16x16x32 path (shape-determined):
// frag(rf=row>>4, kc=k>>5), frag idx = rf*64+kc, 512 BYTES per frag;
// in-frag byte = lane*8 + (k&7), lane = (row&15) | (((k>>3)&3)<<4).

// one-time: both f32 NxN weights -> fp8 e4m3 fragment-major, scaled by 512
__global__ __launch_bounds__(256) void convert_kernel(
    const float* __restrict__ Ww, unsigned char* __restrict__ Wf,
    const float* __restrict__ Tw, unsigned char* __restrict__ Tf, int half) {
  int bid = blockIdx.x;
  const float* src = Ww;
  unsigned char* dst = Wf;
  if (bid >= half) { bid -= half; src = Tw; dst = Tf; }
  const int g = bid * 256 + threadIdx.x;        // one 8-elem group per thread
  const int frag = g >> 6, l = g & 63;
  const int j = (frag >> 6) * 16 + (l & 15);
  const int k = (frag & 63) * 32 + (l >> 4) * 8;
  const float* s = src + (size_t)j * NN + k;
  unsigned lo = pack4_fp8(s[0] * WSCALE, s[1] * WSCALE, s[2] * WSCALE, s[3] * WSCALE);
  unsigned hi = pack4_fp8(s[4] * WSCALE, s[5] * WSCALE, s[6] * WSCALE, s[7] * WSCALE);
  ((unsigned long long*)dst)[g] = ((unsigned long long)hi << 32) | lo;
}

__global__ __launch_bounds__(256) void init_kernel(
    const float* __restrict__ x0,
    unsigned char* __restrict__ U, unsigned char* __restrict__ PSI) {
  const int i = blockIdx.x * 256 + threadIdx.x;
  const int b = i >> 11, j = i & (NN - 1);
  const float r = fmaxf(x0[i], 0.f);
  const int dl = (b & 15) | (((j >> 3) & 3) << 4);
  const size_t fo = ((size_t)((b >> 4) * 64 + (j >> 5))) * 512 + dl * 8 + (j & 7);
  U[fo] = fp8byte(ASCALE * r * r);   // u0 = relu(x0)*relu(x0) (phi==g at t=0)
  PSI[fo] = fp8byte(ASCALE * r);
}

#define LOADST(S, kc) \
  S##a0 = aP0[(size_t)(kc) * 64]; \
  S##a1 = aP1[(size_t)(kc) * 64]; \
  S##b0 = bP0[(size_t)(kc) * 64]; \
  S##b1 = bP1[(size_t)(kc) * 64];
#define DOMFMA(S) \
  acc00 = mfma_fp8(S##a0, S##b0, acc00); \
  acc01 = mfma_fp8(S##a0, S##b1, acc01); \
  acc10 = mfma_fp8(S##a1, S##b0, acc10); \
  acc11 = mfma_fp8(S##a1, S##b1, acc11);

// Block: 64 rows x 32 cols, BOTH GEMMs, grid 256 = 1 block/CU. 8 waves:
//   wv = g*4 + rw*2 + h; g: GEMM, rw: row-half, h: K-half. (R7 structure, fp8.)
__global__ __launch_bounds__(512, 2) void step_kernel(
    const unsigned char* __restrict__ Wf, const unsigned char* __restrict__ Tf,
    const float* __restrict__ Wb, const float* __restrict__ Tb,
    const float* __restrict__ wp2s, const float* __restrict__ ws2p,
    const float* __restrict__ fri,
    const float* __restrict__ Xprev, const float2* __restrict__ SPprev,
    const unsigned char* __restrict__ Uprev, const unsigned char* __restrict__ PSprev,
    float2* __restrict__ SPnew,
    unsigned char* __restrict__ Unew, unsigned char* __restrict__ PSnew,
    float* __restrict__ xsout, float* __restrict__ outFin, int first, int last) {
  __shared__ float eb[8][32][36];   // per-wave 32x32 f32 partials, padded

  const int tid = threadIdx.x;
  const int lane = tid & 63, wv = tid >> 6;
  const int lane15 = lane & 15, kq = lane >> 4;
  const int g = wv >> 2, rw = (wv >> 1) & 1, h = wv & 1;

  // XCD-aware bijective swizzle: XCD x owns col-tiles x*8..x*8+7.
  const int sb = ((blockIdx.x & 7) << 5) + (blockIdx.x >> 3);
  const int colt = sb >> 2, rowt = sb & 3;
  const int b0 = rowt * 64, j0 = colt * 32;

  // ---- epilogue preloads: issue BEFORE the GEMM so latency hides under it ----
  const int erow = tid >> 3;          // 0..63
  const int c4 = (tid & 7) << 2;      // 0,4,...,28
  const int ej = j0 + c4;
  const size_t eidx = (size_t)(b0 + erow) * NN + ej;
  const f32x4 Wb4 = *(const f32x4*)(Wb + ej);
  const f32x4 Tb4 = *(const f32x4*)(Tb + ej);
  const f32x4 wp4 = *(const f32x4*)(wp2s + ej);
  const f32x4 ws4 = *(const f32x4*)(ws2p + ej);
  const f32x4 fr4 = *(const f32x4*)(fri + eidx);
  const f32x4 xv4 = *(const f32x4*)(Xprev + eidx);
  f32x4 sv4, pv4;
  if (first) {
    sv4 = xv4; pv4 = xv4;
  } else {
#pragma unroll
    for (int e = 0; e < 4; e += 2) {
      const f32x4 t0 = *(const f32x4*)(SPprev + eidx + e);     // {s0,p0,s1,p1}
      sv4[e] = t0[0]; pv4[e] = t0[1]; sv4[e + 1] = t0[2]; pv4[e + 1] = t0[3];
    }
  }

  // ---- GEMM streams (fp8, disjoint per wave; B-pair overlap is L1-served) ----
  const unsigned char* Af = g == 0 ? Uprev : PSprev;
  const unsigned char* Bf = g == 0 ? Wf : Tf;
  const int rf0 = rowt * 4 + rw * 2;   // A row-frag base (rows rw*32..+31)
  const int cf0 = colt * 2;            // B col-frag base (cols j0..+31)
  const int kcb = h * 32;              // K-half base (frag-k units)

  const long long* aP0 = (const long long*)Af + ((size_t)rf0 * 64 + kcb) * 64 + lane;
  const long long* aP1 = (const long long*)Af + ((size_t)(rf0 + 1) * 64 + kcb) * 64 + lane;
  const long long* bP0 = (const long long*)Bf + ((size_t)cf0 * 64 + kcb) * 64 + lane;
  const long long* bP1 = (const long long*)Bf + ((size_t)(cf0 + 1) * 64 + kcb) * 64 + lane;

  floatx4 acc00 = {0.f, 0.f, 0.f, 0.f}, acc01 = {0.f, 0.f, 0.f, 0.f};
  floatx4 acc10 = {0.f, 0.f, 0.f, 0.f}, acc11 = {0.f, 0.f, 0.f, 0.f};

  long long Aa0, Aa1, Ab0, Ab1, Ba0, Ba1, Bb0, Bb1, Ca0, Ca1, Cb0, Cb1;
  long long Da0, Da1, Db0, Db1, Ea0, Ea1, Eb0, Eb1, Fa0, Fa1, Fb0, Fb1;
  LOADST(A, 0) LOADST(B, 1) LOADST(C, 2) LOADST(D, 3) LOADST(E, 4) LOADST(F, 5)
  for (int kc = 0; kc < 24; kc += 6) {   // compute 0..23, load 6..29
    DOMFMA(A) LOADST(A, kc + 6)
    DOMFMA(B) LOADST(B, kc + 7)
    DOMFMA(C) LOADST(C, kc + 8)
    DOMFMA(D) LOADST(D, kc + 9)
    DOMFMA(E) LOADST(E, kc + 10)
    DOMFMA(F) LOADST(F, kc + 11)
  }
  DOMFMA(A) LOADST(A, 30)
  DOMFMA(B) LOADST(B, 31)
  DOMFMA(C) DOMFMA(D) DOMFMA(E) DOMFMA(F)
  DOMFMA(A) DOMFMA(B)                    // 32 k-iters total, no OOB loads

  // publish partials: eb[wv][local row][local col]
#pragma unroll
  for (int r = 0; r < 4; ++r) {
    eb[wv][kq * 4 + r][lane15] = acc00[r];
    eb[wv][kq * 4 + r][16 + lane15] = acc01[r];
    eb[wv][16 + kq * 4 + r][lane15] = acc10[r];
    eb[wv][16 + kq * 4 + r][16 + lane15] = acc11[r];
  }
  __syncthreads();

  // ---- vector epilogue: thread owns (row erow, cols ej..ej+3) ----
  const int rl = erow & 31, rh = erow >> 5;
  f32x4 m1, m2;
  {
    const f32x4 p0 = *(const f32x4*)&eb[rh * 2 + 0][rl][c4];
    const f32x4 p1 = *(const f32x4*)&eb[rh * 2 + 1][rl][c4];
    const f32x4 q0 = *(const f32x4*)&eb[4 + rh * 2 + 0][rl][c4];
    const f32x4 q1 = *(const f32x4*)&eb[4 + rh * 2 + 1][rl][c4];
    m1 = (p0 + p1) * ACC_INV;
    m2 = (q0 + q1) * ACC_INV;
  }
  f32x4 xn4;
  float uf[4], pf[4];
#pragma unroll
  for (int e = 0; e < 4; e += 2) {
    f32x4 sp;
#pragma unroll
    for (int q = 0; q < 2; ++q) {
      const int ee = e + q;
      const float xv = xv4[ee], s = sv4[ee], p = pv4[ee];
      const float phi = fmaxf(xv, 0.f), gg = fmaxf(s, 0.f), psi = fmaxf(p, 0.f);
      const float xn = xv + DT_C * (-xv + m1[ee] + Wb4[ee]) * fr4[ee];
      const float sn = p + DT_C * (-s + wp4[ee] * psi + phi);  // base is p (as in source)
      const float pn = p + DT_C * (-p + m2[ee] + Tb4[ee] + ws4[ee] * gg);
      xn4[ee] = xn;
      sp[q * 2] = sn; sp[q * 2 + 1] = pn;
      uf[ee] = ASCALE * fmaxf(xn, 0.f) * fmaxf(sn, 0.f);
      pf[ee] = ASCALE * fmaxf(pn, 0.f);
    }
    *(f32x4*)(SPnew + eidx + e) = sp;    // {s,p,s,p}
  }
  *(f32x4*)(xsout + eidx) = xn4;
  if (last) *(f32x4*)(outFin + eidx) = xn4;
  // next-step operands, fragment-major fp8 (4 consecutive elems, 4B aligned)
  const int b = b0 + erow;
  const int dl = (b & 15) | (((ej >> 3) & 3) << 4);
  const size_t fob = ((size_t)((b >> 4) * 64 + (ej >> 5))) * 512 + dl * 8 + (ej & 7);
  *(unsigned*)(Unew + fob) = pack4_fp8(uf[0], uf[1], uf[2], uf[3]);
  *(unsigned*)(PSnew + fob) = pack4_fp8(pf[0], pf[1], pf[2], pf[3]);
}

extern "C" void kernel_launch(void* const* d_in, const int* in_sizes, int n_in,
                              void* d_out, int out_size, void* d_ws, size_t ws_size,
                              hipStream_t stream) {
  const float* x0   = (const float*)d_in[0];
  const float* fri  = (const float*)d_in[1];
  const float* Ww   = (const float*)d_in[2];
  const float* Wb   = (const float*)d_in[3];
  const float* Tw   = (const float*)d_in[4];
  const float* Tb   = (const float*)d_in[5];
  const float* wp2s = (const float*)d_in[6];
  const float* ws2p = (const float*)d_in[7];
  float* out = (float*)d_out;

  const size_t BN = (size_t)BB * NN;
  const size_t NW = (size_t)NN * NN;
  float2* SP = (float2*)d_ws;                    // interleaved {s,p}
  unsigned char* U0  = (unsigned char*)(SP + BN);
  unsigned char* U1  = U0 + BN;
  unsigned char* PS0 = U1 + BN;
  unsigned char* PS1 = PS0 + BN;
  unsigned char* Wf  = PS1 + BN;
  unsigned char* Tf  = Wf + NW;

  const int chalf = (int)(NW / 2048);            // 8 elems/thread, 256 thr/blk
  convert_kernel<<<2 * chalf, 256, 0, stream>>>(Ww, Wf, Tw, Tf, chalf);
  init_kernel<<<(int)(BN / 256), 256, 0, stream>>>(x0, U0, PS0);

  float* xs = out + BN;  // xs[t] = out + BN + t*BN
  for (int t = 0; t < NSTEPS; ++t) {
    const float* Xprev = (t == 0) ? x0 : (xs + (size_t)(t - 1) * BN);
    const unsigned char* Uprev  = (t & 1) ? U1 : U0;
    const unsigned char* PSprev = (t & 1) ? PS1 : PS0;
    unsigned char* Unew  = (t & 1) ? U0 : U1;
    unsigned char* PSnew = (t & 1) ? PS0 : PS1;
    step_kernel<<<256, 512, 0, stream>>>(Wf, Tf, Wb, Tb, wp2s, ws2p, fri,
                                         Xprev, SP, Uprev, PSprev,
                                         SP, Unew, PSnew,
                                         xs + (size_t)t * BN, out,
                                         (t == 0) ? 1 : 0,
                                         (t == NSTEPS - 1) ? 1 : 0);
  }
}

// Round 12
// 815.393 us; speedup vs baseline: 1.6391x; 1.0455x over previous
//
#include <hip/hip_runtime.h>
#include <hip/hip_bf16.h>

#define BB 256
#define NN 2048
#define NSTEPS 64
#define DT_C 0.1f
// fp8 scaling: weights x512 (2^9), activations x8 (2^3); acc / 4096 (exact).
#define WSCALE 512.0f
#define ASCALE 8.0f
#define ACC_INV (1.0f / 4096.0f)

typedef __attribute__((ext_vector_type(4))) float floatx4;
typedef __attribute__((ext_vector_type(4))) float f32x4;
typedef __attribute__((ext_vector_type(8))) _Float16 half8;
typedef __attribute__((ext_vector_type(4))) _Float16 half4;

__device__ __forceinline__ floatx4 mfma_fp8(long long a, long long b, floatx4 c) {
  return __builtin_amdgcn_mfma_f32_16x16x32_fp8_fp8(a, b, c, 0, 0, 0);
}

// pack 4 f32 -> 4 fp8 e4m3 bytes
__device__ __forceinline__ unsigned pack4_fp8(float a, float b, float c, float d) {
  int lo = __builtin_amdgcn_cvt_pk_fp8_f32(a, b, 0, false);    // bytes 0,1
  int r  = __builtin_amdgcn_cvt_pk_fp8_f32(c, d, lo, true);    // bytes 2,3
  return (unsigned)r;
}
__device__ __forceinline__ unsigned char fp8byte(float v) {
  return (unsigned char)(__builtin_amdgcn_cvt_pk_fp8_f32(v, 0.f, 0, false) & 0xff);
}

// ---------------- fragment-major fp8 layouts (verified R11) ----------------
// frag(rf=row>>4, kc=k>>5), frag idx = rf*64+kc, 512 BYTES per frag;
// in-frag byte = lane*8 + (k&7), lane = (row&15) | (((k>>3)&3)<<4).

// one-time: both f32 NxN weights -> fp8 e4m3 fragment-major, scaled by 512
__global__ __launch_bounds__(256) void convert_kernel(
    const float* __restrict__ Ww, unsigned char* __restrict__ Wf,
    const float* __restrict__ Tw, unsigned char* __restrict__ Tf, int half) {
  int bid = blockIdx.x;
  const float* src = Ww;
  unsigned char* dst = Wf;
  if (bid >= half) { bid -= half; src = Tw; dst = Tf; }
  const int g = bid * 256 + threadIdx.x;        // one 8-elem group per thread
  const int frag = g >> 6, l = g & 63;
  const int j = (frag >> 6) * 16 + (l & 15);
  const int k = (frag & 63) * 32 + (l >> 4) * 8;
  const float* s = src + (size_t)j * NN + k;
  unsigned lo = pack4_fp8(s[0] * WSCALE, s[1] * WSCALE, s[2] * WSCALE, s[3] * WSCALE);
  unsigned hi = pack4_fp8(s[4] * WSCALE, s[5] * WSCALE, s[6] * WSCALE, s[7] * WSCALE);
  ((unsigned long long*)dst)[g] = ((unsigned long long)hi << 32) | lo;
}

// one-time: U0/PSI0 (fp8 fragment-major) + fri -> fp16 copy
__global__ __launch_bounds__(256) void init_kernel(
    const float* __restrict__ x0, const float* __restrict__ fri,
    unsigned char* __restrict__ U, unsigned char* __restrict__ PSI,
    _Float16* __restrict__ friH) {
  const int i = blockIdx.x * 256 + threadIdx.x;
  friH[i] = (_Float16)fri[i];
  const int b = i >> 11, j = i & (NN - 1);
  const float r = fmaxf(x0[i], 0.f);
  const int dl = (b & 15) | (((j >> 3) & 3) << 4);
  const size_t fo = ((size_t)((b >> 4) * 64 + (j >> 5))) * 512 + dl * 8 + (j & 7);
  U[fo] = fp8byte(ASCALE * r * r);   // u0 = relu(x0)*relu(x0) (phi==g at t=0)
  PSI[fo] = fp8byte(ASCALE * r);
}

#define LOADST(S, kc) \
  S##a0 = aP0[(size_t)(kc) * 64]; \
  S##a1 = aP1[(size_t)(kc) * 64]; \
  S##b0 = bP0[(size_t)(kc) * 64]; \
  S##b1 = bP1[(size_t)(kc) * 64];
#define DOMFMA(S) \
  acc00 = mfma_fp8(S##a0, S##b0, acc00); \
  acc01 = mfma_fp8(S##a0, S##b1, acc01); \
  acc10 = mfma_fp8(S##a1, S##b0, acc10); \
  acc11 = mfma_fp8(S##a1, S##b1, acc11);

// Block: 64 rows x 32 cols, BOTH GEMMs, grid 256 = 1 block/CU. 8 waves:
//   wv = g*4 + rw*2 + h; g: GEMM, rw: row-half, h: K-half. (R7/R11 structure.)
// S,P carried as fp16 pairs {s,p}; fri as fp16 (state-traffic halved).
__global__ __launch_bounds__(512, 2) void step_kernel(
    const unsigned char* __restrict__ Wf, const unsigned char* __restrict__ Tf,
    const float* __restrict__ Wb, const float* __restrict__ Tb,
    const float* __restrict__ wp2s, const float* __restrict__ ws2p,
    const _Float16* __restrict__ friH,
    const float* __restrict__ Xprev, const _Float16* __restrict__ SPprev,
    const unsigned char* __restrict__ Uprev, const unsigned char* __restrict__ PSprev,
    _Float16* __restrict__ SPnew,
    unsigned char* __restrict__ Unew, unsigned char* __restrict__ PSnew,
    float* __restrict__ xsout, float* __restrict__ outFin, int first, int last) {
  __shared__ float eb[8][32][36];   // per-wave 32x32 f32 partials, padded

  const int tid = threadIdx.x;
  const int lane = tid & 63, wv = tid >> 6;
  const int lane15 = lane & 15, kq = lane >> 4;
  const int g = wv >> 2, rw = (wv >> 1) & 1, h = wv & 1;

  // XCD-aware bijective swizzle: XCD x owns col-tiles x*8..x*8+7.
  const int sb = ((blockIdx.x & 7) << 5) + (blockIdx.x >> 3);
  const int colt = sb >> 2, rowt = sb & 3;
  const int b0 = rowt * 64, j0 = colt * 32;

  // ---- epilogue preloads: issue BEFORE the GEMM so latency hides under it ----
  const int erow = tid >> 3;          // 0..63
  const int c4 = (tid & 7) << 2;      // 0,4,...,28
  const int ej = j0 + c4;
  const size_t eidx = (size_t)(b0 + erow) * NN + ej;
  const f32x4 Wb4 = *(const f32x4*)(Wb + ej);
  const f32x4 Tb4 = *(const f32x4*)(Tb + ej);
  const f32x4 wp4 = *(const f32x4*)(wp2s + ej);
  const f32x4 ws4 = *(const f32x4*)(ws2p + ej);
  const half4 fh4 = *(const half4*)(friH + eidx);
  const f32x4 xv4 = *(const f32x4*)(Xprev + eidx);
  f32x4 sv4, pv4;
  if (first) {
    sv4 = xv4; pv4 = xv4;
  } else {
    const half8 spv = *(const half8*)(SPprev + 2 * eidx);   // {s0,p0,...,s3,p3}
#pragma unroll
    for (int e = 0; e < 4; ++e) {
      sv4[e] = (float)spv[2 * e];
      pv4[e] = (float)spv[2 * e + 1];
    }
  }

  // ---- GEMM streams (fp8, disjoint per wave; B-pair overlap is L1-served) ----
  const unsigned char* Af = g == 0 ? Uprev : PSprev;
  const unsigned char* Bf = g == 0 ? Wf : Tf;
  const int rf0 = rowt * 4 + rw * 2;   // A row-frag base (rows rw*32..+31)
  const int cf0 = colt * 2;            // B col-frag base (cols j0..+31)
  const int kcb = h * 32;              // K-half base (frag-k units)

  const long long* aP0 = (const long long*)Af + ((size_t)rf0 * 64 + kcb) * 64 + lane;
  const long long* aP1 = (const long long*)Af + ((size_t)(rf0 + 1) * 64 + kcb) * 64 + lane;
  const long long* bP0 = (const long long*)Bf + ((size_t)cf0 * 64 + kcb) * 64 + lane;
  const long long* bP1 = (const long long*)Bf + ((size_t)(cf0 + 1) * 64 + kcb) * 64 + lane;

  floatx4 acc00 = {0.f, 0.f, 0.f, 0.f}, acc01 = {0.f, 0.f, 0.f, 0.f};
  floatx4 acc10 = {0.f, 0.f, 0.f, 0.f}, acc11 = {0.f, 0.f, 0.f, 0.f};

  long long Aa0, Aa1, Ab0, Ab1, Ba0, Ba1, Bb0, Bb1, Ca0, Ca1, Cb0, Cb1;
  long long Da0, Da1, Db0, Db1, Ea0, Ea1, Eb0, Eb1, Fa0, Fa1, Fb0, Fb1;
  LOADST(A, 0) LOADST(B, 1) LOADST(C, 2) LOADST(D, 3) LOADST(E, 4) LOADST(F, 5)
  for (int kc = 0; kc < 24; kc += 6) {   // compute 0..23, load 6..29
    DOMFMA(A) LOADST(A, kc + 6)
    DOMFMA(B) LOADST(B, kc + 7)
    DOMFMA(C) LOADST(C, kc + 8)
    DOMFMA(D) LOADST(D, kc + 9)
    DOMFMA(E) LOADST(E, kc + 10)
    DOMFMA(F) LOADST(F, kc + 11)
  }
  DOMFMA(A) LOADST(A, 30)
  DOMFMA(B) LOADST(B, 31)
  DOMFMA(C) DOMFMA(D) DOMFMA(E) DOMFMA(F)
  DOMFMA(A) DOMFMA(B)                    // 32 k-iters total, no OOB loads

  // publish partials: eb[wv][local row][local col]
#pragma unroll
  for (int r = 0; r < 4; ++r) {
    eb[wv][kq * 4 + r][lane15] = acc00[r];
    eb[wv][kq * 4 + r][16 + lane15] = acc01[r];
    eb[wv][16 + kq * 4 + r][lane15] = acc10[r];
    eb[wv][16 + kq * 4 + r][16 + lane15] = acc11[r];
  }
  __syncthreads();

  // ---- vector epilogue: thread owns (row erow, cols ej..ej+3) ----
  const int rl = erow & 31, rh = erow >> 5;
  f32x4 m1, m2;
  {
    const f32x4 p0 = *(const f32x4*)&eb[rh * 2 + 0][rl][c4];
    const f32x4 p1 = *(const f32x4*)&eb[rh * 2 + 1][rl][c4];
    const f32x4 q0 = *(const f32x4*)&eb[4 + rh * 2 + 0][rl][c4];
    const f32x4 q1 = *(const f32x4*)&eb[4 + rh * 2 + 1][rl][c4];
    m1 = (p0 + p1) * ACC_INV;
    m2 = (q0 + q1) * ACC_INV;
  }
  f32x4 xn4;
  half8 spn;
  float uf[4], pf[4];
#pragma unroll
  for (int e = 0; e < 4; ++e) {
    const float xv = xv4[e], s = sv4[e], p = pv4[e];
    const float phi = fmaxf(xv, 0.f), gg = fmaxf(s, 0.f), psi = fmaxf(p, 0.f);
    const float xn = xv + DT_C * (-xv + m1[e] + Wb4[e]) * (float)fh4[e];
    const float sn = p + DT_C * (-s + wp4[e] * psi + phi);   // base is p (as in source)
    const float pn = p + DT_C * (-p + m2[e] + Tb4[e] + ws4[e] * gg);
    xn4[e] = xn;
    spn[2 * e] = (_Float16)sn;
    spn[2 * e + 1] = (_Float16)pn;
    uf[e] = ASCALE * fmaxf(xn, 0.f) * fmaxf(sn, 0.f);
    pf[e] = ASCALE * fmaxf(pn, 0.f);
  }
  *(half8*)(SPnew + 2 * eidx) = spn;
  *(f32x4*)(xsout + eidx) = xn4;
  if (last) *(f32x4*)(outFin + eidx) = xn4;
  // next-step operands, fragment-major fp8 (4 consecutive elems, 4B aligned)
  const int b = b0 + erow;
  const int dl = (b & 15) | (((ej >> 3) & 3) << 4);
  const size_t fob = ((size_t)((b >> 4) * 64 + (ej >> 5))) * 512 + dl * 8 + (ej & 7);
  *(unsigned*)(Unew + fob) = pack4_fp8(uf[0], uf[1], uf[2], uf[3]);
  *(unsigned*)(PSnew + fob) = pack4_fp8(pf[0], pf[1], pf[2], pf[3]);
}

extern "C" void kernel_launch(void* const* d_in, const int* in_sizes, int n_in,
                              void* d_out, int out_size, void* d_ws, size_t ws_size,
                              hipStream_t stream) {
  const float* x0   = (const float*)d_in[0];
  const float* fri  = (const float*)d_in[1];
  const float* Ww   = (const float*)d_in[2];
  const float* Wb   = (const float*)d_in[3];
  const float* Tw   = (const float*)d_in[4];
  const float* Tb   = (const float*)d_in[5];
  const float* wp2s = (const float*)d_in[6];
  const float* ws2p = (const float*)d_in[7];
  float* out = (float*)d_out;

  const size_t BN = (size_t)BB * NN;
  const size_t NW = (size_t)NN * NN;
  _Float16* SP   = (_Float16*)d_ws;              // interleaved {s,p} fp16, 2 MB
  _Float16* friH = SP + 2 * BN;                  // fp16 fri, 1 MB
  unsigned char* U0  = (unsigned char*)(friH + BN);
  unsigned char* U1  = U0 + BN;
  unsigned char* PS0 = U1 + BN;
  unsigned char* PS1 = PS0 + BN;
  unsigned char* Wf  = PS1 + BN;
  unsigned char* Tf  = Wf + NW;

  const int chalf = (int)(NW / 2048);            // 8 elems/thread, 256 thr/blk
  convert_kernel<<<2 * chalf, 256, 0, stream>>>(Ww, Wf, Tw, Tf, chalf);
  init_kernel<<<(int)(BN / 256), 256, 0, stream>>>(x0, fri, U0, PS0, friH);

  float* xs = out + BN;  // xs[t] = out + BN + t*BN
  for (int t = 0; t < NSTEPS; ++t) {
    const float* Xprev = (t == 0) ? x0 : (xs + (size_t)(t - 1) * BN);
    const unsigned char* Uprev  = (t & 1) ? U1 : U0;
    const unsigned char* PSprev = (t & 1) ? PS1 : PS0;
    unsigned char* Unew  = (t & 1) ? U0 : U1;
    unsigned char* PSnew = (t & 1) ? PS0 : PS1;
    step_kernel<<<256, 512, 0, stream>>>(Wf, Tf, Wb, Tb, wp2s, ws2p, friH,
                                         Xprev, SP, Uprev, PSprev,
                                         SP, Unew, PSnew,
                                         xs + (size_t)t * BN, out,
                                         (t == 0) ? 1 : 0,
                                         (t == NSTEPS - 1) ? 1 : 0);
  }
}